// Round 2
// baseline (2203.890 us; speedup 1.0000x reference)
//
#include <hip/hip_runtime.h>
#include <cstdint>
#include <cstddef>

#define NN 4096
#define ITERS 50
#define TB 256            // tile is TB x TB
#define TSTRIDE 264       // halves per LDS tile row (256 + 8 pad -> 528 B, 16B-aligned)
#define NBLK 256          // 16 x 16 blocks
#define NTHR 1024

typedef _Float16 half4v __attribute__((ext_vector_type(4)));
typedef _Float16 half8v __attribute__((ext_vector_type(8)));

#define T_BYTES (TB * TSTRIDE * 2)                              // 135168
#define SMEM_BYTES (T_BYTES + 4096 + 1024 + 1024 + 1024)        // 142336

// ---------------------------------------------------------------------------
// Cooperative LDS-resident Sinkhorn.
//   E = exp(M) as fp16 tile in LDS. Per iteration:
//     rr[i] = 1/sum_j E[i,j]*rc[j]   (row step, fully overwrites r)
//     rc[j] = 1/sum_i E[i,j]*rr[i]   (col step, uses NEW rr)
//   out = max(exp(M)*rr[i]*rc[j], 1e-9)  computed in fp32 from M directly.
// Cross-block: rpart[16][4096], cpart[16][4096] partials + grid barrier.
// ---------------------------------------------------------------------------

__device__ __forceinline__ void grid_sync(unsigned* __restrict__ bar, unsigned gen) {
    __syncthreads();
    if (threadIdx.x == 0) {
        unsigned* cnt  = bar;        // arrivals, monotone (never reset)
        unsigned* flag = bar + 32;   // released generation (separate line)
        unsigned prev = __hip_atomic_fetch_add(cnt, 1u, __ATOMIC_ACQ_REL,
                                               __HIP_MEMORY_SCOPE_AGENT);
        if (prev == gen * NBLK - 1u) {
            __hip_atomic_store(flag, gen, __ATOMIC_RELEASE, __HIP_MEMORY_SCOPE_AGENT);
        } else {
            while (__hip_atomic_load(flag, __ATOMIC_ACQUIRE,
                                     __HIP_MEMORY_SCOPE_AGENT) < gen) {
                __builtin_amdgcn_s_sleep(2);
            }
        }
    }
    __syncthreads();
}

__global__ void sk_bar_init(unsigned* __restrict__ bar) {
    bar[threadIdx.x] = 0u;
}

__global__ __launch_bounds__(NTHR) void sk_coop(const float* __restrict__ M,
                                                float* __restrict__ out,
                                                float* __restrict__ rpart,
                                                float* __restrict__ cpart,
                                                unsigned* __restrict__ bar) {
    extern __shared__ char smem[];
    _Float16* T     = (_Float16*)smem;                 // [TB][TSTRIDE]
    float*    red   = (float*)(smem + T_BYTES);        // [4][256]
    float*    colacc = red + 1024;                     // [256]
    float*    rcv   = colacc + 256;                    // [256]
    float*    rrv   = rcv + 256;                       // [256]

    const int t  = threadIdx.x;
    const int bi = blockIdx.x >> 4;    // row group
    const int bj = blockIdx.x & 15;    // col group
    const float* Mt = M + ((size_t)bi * TB) * NN + (size_t)bj * TB;

    // ---- load tile: E = exp(M) -> fp16 LDS ----
    #pragma unroll
    for (int i = 0; i < 16; ++i) {
        int idx = t + i * NTHR;
        int r = idx >> 6, c4 = idx & 63;
        float4 m = *(const float4*)(Mt + (size_t)r * NN + c4 * 4);
        half4v h;
        h[0] = (_Float16)__expf(m.x);
        h[1] = (_Float16)__expf(m.y);
        h[2] = (_Float16)__expf(m.z);
        h[3] = (_Float16)__expf(m.w);
        *(half4v*)&T[r * TSTRIDE + c4 * 4] = h;
    }

    unsigned gen = 0;
    for (int it = 0; it < ITERS; ++it) {
        // ---- rc prep: rcv[c] = 1 / sum_g cpart[g][bj*TB+c] ----
        if (t < TB) {
            if (it == 0) {
                rcv[t] = 1.0f;
            } else {
                float s = 0.0f;
                #pragma unroll
                for (int g = 0; g < 16; ++g)
                    s += cpart[(size_t)g * NN + bj * TB + t];
                rcv[t] = 1.0f / s;
            }
        }
        __syncthreads();

        // ---- phase A: row sums. thread: row = t&255, q = t>>8 owns 64 cols ----
        {
            const int row = t & 255, q = t >> 8;
            const half8v* Trow = (const half8v*)&T[row * TSTRIDE + q * 64];
            const float4* rc4  = (const float4*)(rcv + q * 64);
            float s = 0.0f;
            #pragma unroll
            for (int k = 0; k < 8; ++k) {
                half8v hv = Trow[k];
                float4 c0 = rc4[2 * k];
                float4 c1 = rc4[2 * k + 1];
                s += (float)hv[0] * c0.x + (float)hv[1] * c0.y +
                     (float)hv[2] * c0.z + (float)hv[3] * c0.w +
                     (float)hv[4] * c1.x + (float)hv[5] * c1.y +
                     (float)hv[6] * c1.z + (float)hv[7] * c1.w;
            }
            red[q * 256 + row] = s;
        }
        __syncthreads();
        if (t < TB) {
            float s = red[t] + red[256 + t] + red[512 + t] + red[768 + t];
            rpart[(size_t)bj * NN + bi * TB + t] = s;
        }
        gen++; grid_sync(bar, gen);

        // ---- rr prep + zero colacc ----
        if (t < TB) {
            float s = 0.0f;
            #pragma unroll
            for (int g = 0; g < 16; ++g)
                s += rpart[(size_t)g * NN + bi * TB + t];
            rrv[t] = 1.0f / s;
        } else if (t < 512) {
            colacc[t - 256] = 0.0f;
        }
        __syncthreads();

        // ---- phase B: col sums. thread: ch = t&31 (8 cols), sub = t>>5 (8 rows) ----
        {
            const int ch = t & 31, sub = t >> 5;
            float acc[8] = {0, 0, 0, 0, 0, 0, 0, 0};
            #pragma unroll
            for (int r = 0; r < 8; ++r) {
                const int row = sub * 8 + r;
                half8v hv = *(const half8v*)&T[row * TSTRIDE + ch * 8];
                float rr = rrv[row];
                #pragma unroll
                for (int j = 0; j < 8; ++j) acc[j] += (float)hv[j] * rr;
            }
            #pragma unroll
            for (int j = 0; j < 8; ++j) acc[j] += __shfl_down(acc[j], 32);
            const int lane = t & 63;
            if (lane < 32) {
                const int rot = (lane >> 2) & 7;
                #pragma unroll
                for (int jj = 0; jj < 8; ++jj) {
                    int j = (jj + rot) & 7;
                    atomicAdd(&colacc[ch * 8 + j], acc[j]);
                }
            }
        }
        __syncthreads();
        if (t < TB) cpart[(size_t)bi * NN + bj * TB + t] = colacc[t];
        gen++; grid_sync(bar, gen);
    }

    // ---- epilogue: final rc, then out = max(exp(M)*rr*rc, 1e-9) in fp32 ----
    if (t < TB) {
        float s = 0.0f;
        #pragma unroll
        for (int g = 0; g < 16; ++g)
            s += cpart[(size_t)g * NN + bj * TB + t];
        rcv[t] = 1.0f / s;
    }
    __syncthreads();

    float* outt = out + ((size_t)bi * TB) * NN + (size_t)bj * TB;
    #pragma unroll
    for (int i = 0; i < 16; ++i) {
        int idx = t + i * NTHR;
        int r = idx >> 6, c4 = idx & 63;
        float4 m = *(const float4*)(Mt + (size_t)r * NN + c4 * 4);
        float rr = rrv[r];
        float4 c = ((const float4*)rcv)[c4];
        float4 o;
        o.x = fmaxf(__expf(m.x) * rr * c.x, 1e-9f);
        o.y = fmaxf(__expf(m.y) * rr * c.y, 1e-9f);
        o.z = fmaxf(__expf(m.z) * rr * c.z, 1e-9f);
        o.w = fmaxf(__expf(m.w) * rr * c.w, 1e-9f);
        *(float4*)(outt + (size_t)r * NN + c4 * 4) = o;
    }
}

// ===========================================================================
// Fallback multi-kernel path (round-1, known-good) if cooperative launch or
// the 139 KiB dynamic-LDS request is unavailable.
// ===========================================================================

__global__ __launch_bounds__(256) void sk_init(float* __restrict__ rc,
                                               float* __restrict__ c_sum) {
    int j = blockIdx.x * 256 + threadIdx.x;
    rc[j] = 1.0f;
    c_sum[j] = 0.0f;
}

__global__ __launch_bounds__(256) void sk_exp(const float* __restrict__ M,
                                              float* __restrict__ E) {
    size_t idx = ((size_t)blockIdx.x * 256 + threadIdx.x) * 4;
    float4 m = *(const float4*)(M + idx);
    float4 e;
    e.x = __expf(m.x); e.y = __expf(m.y); e.z = __expf(m.z); e.w = __expf(m.w);
    *(float4*)(E + idx) = e;
}

template<bool HAS_E>
__global__ __launch_bounds__(256) void sk_row(const float* __restrict__ Mat,
                                              const float* __restrict__ rc,
                                              float* __restrict__ rr) {
    const int wave = threadIdx.x >> 6;
    const int lane = threadIdx.x & 63;
    const int row  = blockIdx.x * 4 + wave;
    const float4* __restrict__ Mrow = (const float4*)(Mat + (size_t)row * NN);
    const float4* __restrict__ RC   = (const float4*)rc;
    float s = 0.0f;
    #pragma unroll 4
    for (int k = lane; k < NN / 4; k += 64) {
        float4 m = Mrow[k];
        float4 c = RC[k];
        if (!HAS_E) {
            m.x = __expf(m.x); m.y = __expf(m.y);
            m.z = __expf(m.z); m.w = __expf(m.w);
        }
        s += m.x * c.x + m.y * c.y + m.z * c.z + m.w * c.w;
    }
    #pragma unroll
    for (int off = 32; off > 0; off >>= 1) s += __shfl_down(s, off, 64);
    if (lane == 0) rr[row] = 1.0f / s;
}

template<bool HAS_E>
__global__ __launch_bounds__(256) void sk_col(const float* __restrict__ Mat,
                                              const float* __restrict__ rr,
                                              float* __restrict__ c_sum) {
    const int j  = blockIdx.x * 256 + threadIdx.x;
    const int r0 = blockIdx.y * 64;
    const float* __restrict__ rrp = rr + r0;
    const float* __restrict__ p   = Mat + (size_t)r0 * NN + j;
    float s = 0.0f;
    #pragma unroll 8
    for (int i = 0; i < 64; ++i) {
        float m = p[(size_t)i * NN];
        if (!HAS_E) m = __expf(m);
        s += m * rrp[i];
    }
    atomicAdd(&c_sum[j], s);
}

__global__ __launch_bounds__(256) void sk_recip(float* __restrict__ c_sum,
                                                float* __restrict__ rc) {
    int j = blockIdx.x * 256 + threadIdx.x;
    rc[j] = 1.0f / c_sum[j];
    c_sum[j] = 0.0f;
}

template<bool HAS_E>
__global__ __launch_bounds__(256) void sk_final(const float* __restrict__ Mat,
                                                const float* __restrict__ rr,
                                                const float* __restrict__ rc,
                                                float* __restrict__ out) {
    const int row = blockIdx.y;
    const int c4  = blockIdx.x * 256 + threadIdx.x;
    float4 m = ((const float4*)(Mat + (size_t)row * NN))[c4];
    if (!HAS_E) {
        m.x = __expf(m.x); m.y = __expf(m.y);
        m.z = __expf(m.z); m.w = __expf(m.w);
    }
    float4 c = ((const float4*)rc)[c4];
    float  r = rr[row];
    float4 o;
    o.x = fmaxf(m.x * r * c.x, 1e-9f);
    o.y = fmaxf(m.y * r * c.y, 1e-9f);
    o.z = fmaxf(m.z * r * c.z, 1e-9f);
    o.w = fmaxf(m.w * r * c.w, 1e-9f);
    ((float4*)out)[(size_t)row * (NN / 4) + c4] = o;
}

static void launch_fallback(const float* M, float* out, char* ws, size_t ws_size,
                            hipStream_t stream) {
    float* rc    = (float*)(ws);
    float* rr    = (float*)(ws + 16 * 1024);
    float* c_sum = (float*)(ws + 32 * 1024);
    float* E     = (float*)(ws + 64 * 1024);

    const size_t need_e = 64 * 1024 + (size_t)NN * NN * sizeof(float);
    const bool   has_e  = ws_size >= need_e;

    sk_init<<<NN / 256, 256, 0, stream>>>(rc, c_sum);

    const float* Mat = M;
    if (has_e) {
        sk_exp<<<(NN * (size_t)NN) / 1024, 256, 0, stream>>>(M, E);
        Mat = E;
    }

    dim3 gcol(16, 64);
    for (int it = 0; it < ITERS; ++it) {
        if (has_e) sk_row<true ><<<NN / 4, 256, 0, stream>>>(Mat, rc, rr);
        else       sk_row<false><<<NN / 4, 256, 0, stream>>>(Mat, rc, rr);
        if (has_e) sk_col<true ><<<gcol, 256, 0, stream>>>(Mat, rr, c_sum);
        else       sk_col<false><<<gcol, 256, 0, stream>>>(Mat, rr, c_sum);
        sk_recip<<<NN / 256, 256, 0, stream>>>(c_sum, rc);
    }

    dim3 gfin(4, NN);
    if (has_e) sk_final<true ><<<gfin, 256, 0, stream>>>(Mat, rr, rc, out);
    else       sk_final<false><<<gfin, 256, 0, stream>>>(Mat, rr, rc, out);
}

extern "C" void kernel_launch(void* const* d_in, const int* in_sizes, int n_in,
                              void* d_out, int out_size, void* d_ws, size_t ws_size,
                              hipStream_t stream) {
    const float* M   = (const float*)d_in[0];
    float*       out = (float*)d_out;
    char*        ws  = (char*)d_ws;

    // coop-path workspace: bar (256 B) | rpart 16*4096 f32 | cpart 16*4096 f32
    unsigned* bar   = (unsigned*)ws;
    float*    rpart = (float*)(ws + 1024);
    float*    cpart = (float*)(ws + 1024 + 16 * NN * sizeof(float));
    const size_t ws_need = 1024 + 2 * 16 * NN * sizeof(float);

    int dev = 0;
    (void)hipGetDevice(&dev);
    int coop = 0;
    (void)hipDeviceGetAttribute(&coop, hipDeviceAttributeCooperativeLaunch, dev);
    hipError_t eattr = hipFuncSetAttribute(
        (const void*)sk_coop, hipFuncAttributeMaxDynamicSharedMemorySize, SMEM_BYTES);

    bool done = false;
    if (coop && eattr == hipSuccess && ws_size >= ws_need) {
        sk_bar_init<<<1, 64, 0, stream>>>(bar);
        void* args[5] = {(void*)&M, (void*)&out, (void*)&rpart, (void*)&cpart,
                         (void*)&bar};
        hipError_t e = hipLaunchCooperativeKernel((void*)sk_coop, dim3(NBLK),
                                                  dim3(NTHR), args, SMEM_BYTES,
                                                  stream);
        done = (e == hipSuccess);
    }
    if (!done) launch_fallback(M, out, ws, ws_size, stream);
}

// Round 3
// 1436.235 us; speedup vs baseline: 1.5345x; 1.5345x over previous
//
#include <hip/hip_runtime.h>
#include <cstdint>
#include <cstddef>

#define NN 4096
#define ITERS 50
#define TB 256            // tile is TB x TB
#define TSTRIDE 264       // halves per LDS tile row (256 + 8 pad; stride%32==4 -> conflict-free b128)
#define NBLK 256          // 16 x 16 blocks
#define NTHR 1024

typedef _Float16 half4v __attribute__((ext_vector_type(4)));
typedef _Float16 half8v __attribute__((ext_vector_type(8)));

#define T_BYTES (TB * TSTRIDE * 2)                              // 135168
#define SMEM_BYTES (T_BYTES + 4096 + 1024 + 1024 + 1024)        // 142336

#define SCOPE __HIP_MEMORY_SCOPE_AGENT

// ---------------------------------------------------------------------------
// Cooperative LDS-resident Sinkhorn, group-local sync (NO global barrier).
//   E = exp(M) as fp16 tile in LDS. Per iteration:
//     rr[i] = 1/sum_j E[i,j]*rc[j]   (row step)
//     rc[j] = 1/sum_i E[i,j]*rr[i]   (col step, uses NEW rr)
// Cross-block: rpart/cpart double-buffered by iteration parity; sync via
// per-block generation flags (plain release store + 16-lane acquire poll of
// the owning group's cacheline). Block (bi,bj) only syncs with row-group
// (bi,*) for rpart and col-group (*,bj) for cpart; transitivity covers the
// rest, parity double-buffering removes the lap hazard.
// ---------------------------------------------------------------------------

__global__ void sk_flag_init(unsigned* __restrict__ flags) {
    flags[threadIdx.x] = 0u;   // 512 words: flag_r[256] + flag_c[256]
}

__global__ __launch_bounds__(NTHR) void sk_coop(const float* __restrict__ M,
                                                float* __restrict__ out,
                                                float* __restrict__ rpart,
                                                float* __restrict__ cpart,
                                                unsigned* __restrict__ flag_r,
                                                unsigned* __restrict__ flag_c) {
    extern __shared__ char smem[];
    _Float16* T      = (_Float16*)smem;                // [TB][TSTRIDE]
    float*    red    = (float*)(smem + T_BYTES);       // [4][256]
    float*    colacc = red + 1024;                     // [256]
    float*    rcv    = colacc + 256;                   // [256]
    float*    rrv    = rcv + 256;                      // [256]

    const int t  = threadIdx.x;
    const int bi = blockIdx.x >> 4;    // row group
    const int bj = blockIdx.x & 15;    // col group
    const float* Mt = M + ((size_t)bi * TB) * NN + (size_t)bj * TB;

    // ---- load tile: E = exp(M) -> fp16 LDS ----
    #pragma unroll
    for (int i = 0; i < 16; ++i) {
        int idx = t + i * NTHR;
        int r = idx >> 6, c4 = idx & 63;
        float4 m = *(const float4*)(Mt + (size_t)r * NN + c4 * 4);
        half4v h;
        h[0] = (_Float16)__expf(m.x);
        h[1] = (_Float16)__expf(m.y);
        h[2] = (_Float16)__expf(m.z);
        h[3] = (_Float16)__expf(m.w);
        *(half4v*)&T[r * TSTRIDE + c4 * 4] = h;
    }

    for (int it = 0; it < ITERS; ++it) {
        const int par = it & 1;
        float* rp = rpart + (size_t)par * 16 * NN;
        float* cp = cpart + (size_t)par * 16 * NN;

        // ---- rc prep: wait col-group phase-B(it-1), rcv = 1/colsum ----
        if (it == 0) {
            if (t < TB) rcv[t] = 1.0f;
        } else {
            if (t < 16) {
                const unsigned want = (unsigned)it;
                while (__hip_atomic_load(&flag_c[t * 16 + bj], __ATOMIC_ACQUIRE,
                                         SCOPE) < want) {
                    __builtin_amdgcn_s_sleep(1);
                }
            }
            __syncthreads();
            if (t < TB) {
                const float* cprev = cpart + (size_t)((it - 1) & 1) * 16 * NN;
                float s = 0.0f;
                #pragma unroll
                for (int g = 0; g < 16; ++g)
                    s += cprev[(size_t)g * NN + bj * TB + t];
                rcv[t] = 1.0f / s;
            }
        }
        __syncthreads();

        // ---- phase A: row sums. thread: row = t&255, q = t>>8 owns 64 cols ----
        {
            const int row = t & 255, q = t >> 8;
            const half8v* Trow = (const half8v*)&T[row * TSTRIDE + q * 64];
            const float4* rc4  = (const float4*)(rcv + q * 64);
            float s = 0.0f;
            #pragma unroll
            for (int k = 0; k < 8; ++k) {
                half8v hv = Trow[k];
                float4 c0 = rc4[2 * k];
                float4 c1 = rc4[2 * k + 1];
                s += (float)hv[0] * c0.x + (float)hv[1] * c0.y +
                     (float)hv[2] * c0.z + (float)hv[3] * c0.w +
                     (float)hv[4] * c1.x + (float)hv[5] * c1.y +
                     (float)hv[6] * c1.z + (float)hv[7] * c1.w;
            }
            red[q * 256 + row] = s;
        }
        __syncthreads();
        if (t < TB) {
            float s = red[t] + red[256 + t] + red[512 + t] + red[768 + t];
            rp[(size_t)bj * NN + bi * TB + t] = s;
        }
        __syncthreads();

        // ---- signal phase A done; wait row-group; rr prep ----
        if (t == 0)
            __hip_atomic_store(&flag_r[bi * 16 + bj], (unsigned)(it + 1),
                               __ATOMIC_RELEASE, SCOPE);
        if (t < 16) {
            const unsigned want = (unsigned)(it + 1);
            while (__hip_atomic_load(&flag_r[bi * 16 + t], __ATOMIC_ACQUIRE,
                                     SCOPE) < want) {
                __builtin_amdgcn_s_sleep(1);
            }
        }
        __syncthreads();
        if (t < TB) {
            float s = 0.0f;
            #pragma unroll
            for (int g = 0; g < 16; ++g)
                s += rp[(size_t)g * NN + bi * TB + t];
            rrv[t] = 1.0f / s;
        } else if (t < 512) {
            colacc[t - 256] = 0.0f;
        }
        __syncthreads();

        // ---- phase B: col sums. thread: ch = t&31 (8 cols), sub = t>>5 (8 rows) ----
        {
            const int ch = t & 31, sub = t >> 5;
            float acc[8] = {0, 0, 0, 0, 0, 0, 0, 0};
            #pragma unroll
            for (int r = 0; r < 8; ++r) {
                const int row = sub * 8 + r;
                half8v hv = *(const half8v*)&T[row * TSTRIDE + ch * 8];
                float rr = rrv[row];
                #pragma unroll
                for (int j = 0; j < 8; ++j) acc[j] += (float)hv[j] * rr;
            }
            #pragma unroll
            for (int j = 0; j < 8; ++j) acc[j] += __shfl_down(acc[j], 32);
            const int lane = t & 63;
            if (lane < 32) {
                const int rot = (lane >> 2) & 7;
                #pragma unroll
                for (int jj = 0; jj < 8; ++jj) {
                    int j = (jj + rot) & 7;
                    atomicAdd(&colacc[ch * 8 + j], acc[j]);
                }
            }
        }
        __syncthreads();
        if (t < TB) cp[(size_t)bi * NN + bj * TB + t] = colacc[t];
        __syncthreads();
        if (t == 0)
            __hip_atomic_store(&flag_c[bi * 16 + bj], (unsigned)(it + 1),
                               __ATOMIC_RELEASE, SCOPE);
    }

    // ---- epilogue: wait col-group final, rc, then out = max(exp(M)*rr*rc,1e-9) ----
    if (t < 16) {
        while (__hip_atomic_load(&flag_c[t * 16 + bj], __ATOMIC_ACQUIRE,
                                 SCOPE) < (unsigned)ITERS) {
            __builtin_amdgcn_s_sleep(1);
        }
    }
    __syncthreads();
    if (t < TB) {
        const float* cl = cpart + (size_t)((ITERS - 1) & 1) * 16 * NN;
        float s = 0.0f;
        #pragma unroll
        for (int g = 0; g < 16; ++g)
            s += cl[(size_t)g * NN + bj * TB + t];
        rcv[t] = 1.0f / s;
    }
    __syncthreads();

    float* outt = out + ((size_t)bi * TB) * NN + (size_t)bj * TB;
    #pragma unroll
    for (int i = 0; i < 16; ++i) {
        int idx = t + i * NTHR;
        int r = idx >> 6, c4 = idx & 63;
        float4 m = *(const float4*)(Mt + (size_t)r * NN + c4 * 4);
        float rr = rrv[r];
        float4 c = ((const float4*)rcv)[c4];
        float4 o;
        o.x = fmaxf(__expf(m.x) * rr * c.x, 1e-9f);
        o.y = fmaxf(__expf(m.y) * rr * c.y, 1e-9f);
        o.z = fmaxf(__expf(m.z) * rr * c.z, 1e-9f);
        o.w = fmaxf(__expf(m.w) * rr * c.w, 1e-9f);
        *(float4*)(outt + (size_t)r * NN + c4 * 4) = o;
    }
}

// ===========================================================================
// Fallback multi-kernel path (round-1, known-good).
// ===========================================================================

__global__ __launch_bounds__(256) void sk_init(float* __restrict__ rc,
                                               float* __restrict__ c_sum) {
    int j = blockIdx.x * 256 + threadIdx.x;
    rc[j] = 1.0f;
    c_sum[j] = 0.0f;
}

__global__ __launch_bounds__(256) void sk_exp(const float* __restrict__ M,
                                              float* __restrict__ E) {
    size_t idx = ((size_t)blockIdx.x * 256 + threadIdx.x) * 4;
    float4 m = *(const float4*)(M + idx);
    float4 e;
    e.x = __expf(m.x); e.y = __expf(m.y); e.z = __expf(m.z); e.w = __expf(m.w);
    *(float4*)(E + idx) = e;
}

template<bool HAS_E>
__global__ __launch_bounds__(256) void sk_row(const float* __restrict__ Mat,
                                              const float* __restrict__ rc,
                                              float* __restrict__ rr) {
    const int wave = threadIdx.x >> 6;
    const int lane = threadIdx.x & 63;
    const int row  = blockIdx.x * 4 + wave;
    const float4* __restrict__ Mrow = (const float4*)(Mat + (size_t)row * NN);
    const float4* __restrict__ RC   = (const float4*)rc;
    float s = 0.0f;
    #pragma unroll 4
    for (int k = lane; k < NN / 4; k += 64) {
        float4 m = Mrow[k];
        float4 c = RC[k];
        if (!HAS_E) {
            m.x = __expf(m.x); m.y = __expf(m.y);
            m.z = __expf(m.z); m.w = __expf(m.w);
        }
        s += m.x * c.x + m.y * c.y + m.z * c.z + m.w * c.w;
    }
    #pragma unroll
    for (int off = 32; off > 0; off >>= 1) s += __shfl_down(s, off, 64);
    if (lane == 0) rr[row] = 1.0f / s;
}

template<bool HAS_E>
__global__ __launch_bounds__(256) void sk_col(const float* __restrict__ Mat,
                                              const float* __restrict__ rr,
                                              float* __restrict__ c_sum) {
    const int j  = blockIdx.x * 256 + threadIdx.x;
    const int r0 = blockIdx.y * 64;
    const float* __restrict__ rrp = rr + r0;
    const float* __restrict__ p   = Mat + (size_t)r0 * NN + j;
    float s = 0.0f;
    #pragma unroll 8
    for (int i = 0; i < 64; ++i) {
        float m = p[(size_t)i * NN];
        if (!HAS_E) m = __expf(m);
        s += m * rrp[i];
    }
    atomicAdd(&c_sum[j], s);
}

__global__ __launch_bounds__(256) void sk_recip(float* __restrict__ c_sum,
                                                float* __restrict__ rc) {
    int j = blockIdx.x * 256 + threadIdx.x;
    rc[j] = 1.0f / c_sum[j];
    c_sum[j] = 0.0f;
}

template<bool HAS_E>
__global__ __launch_bounds__(256) void sk_final(const float* __restrict__ Mat,
                                                const float* __restrict__ rr,
                                                const float* __restrict__ rc,
                                                float* __restrict__ out) {
    const int row = blockIdx.y;
    const int c4  = blockIdx.x * 256 + threadIdx.x;
    float4 m = ((const float4*)(Mat + (size_t)row * NN))[c4];
    if (!HAS_E) {
        m.x = __expf(m.x); m.y = __expf(m.y);
        m.z = __expf(m.z); m.w = __expf(m.w);
    }
    float4 c = ((const float4*)rc)[c4];
    float  r = rr[row];
    float4 o;
    o.x = fmaxf(m.x * r * c.x, 1e-9f);
    o.y = fmaxf(m.y * r * c.y, 1e-9f);
    o.z = fmaxf(m.z * r * c.z, 1e-9f);
    o.w = fmaxf(m.w * r * c.w, 1e-9f);
    ((float4*)out)[(size_t)row * (NN / 4) + c4] = o;
}

static void launch_fallback(const float* M, float* out, char* ws, size_t ws_size,
                            hipStream_t stream) {
    float* rc    = (float*)(ws);
    float* rr    = (float*)(ws + 16 * 1024);
    float* c_sum = (float*)(ws + 32 * 1024);
    float* E     = (float*)(ws + 64 * 1024);

    const size_t need_e = 64 * 1024 + (size_t)NN * NN * sizeof(float);
    const bool   has_e  = ws_size >= need_e;

    sk_init<<<NN / 256, 256, 0, stream>>>(rc, c_sum);

    const float* Mat = M;
    if (has_e) {
        sk_exp<<<(NN * (size_t)NN) / 1024, 256, 0, stream>>>(M, E);
        Mat = E;
    }

    dim3 gcol(16, 64);
    for (int it = 0; it < ITERS; ++it) {
        if (has_e) sk_row<true ><<<NN / 4, 256, 0, stream>>>(Mat, rc, rr);
        else       sk_row<false><<<NN / 4, 256, 0, stream>>>(Mat, rc, rr);
        if (has_e) sk_col<true ><<<gcol, 256, 0, stream>>>(Mat, rr, c_sum);
        else       sk_col<false><<<gcol, 256, 0, stream>>>(Mat, rr, c_sum);
        sk_recip<<<NN / 256, 256, 0, stream>>>(c_sum, rc);
    }

    dim3 gfin(4, NN);
    if (has_e) sk_final<true ><<<gfin, 256, 0, stream>>>(Mat, rr, rc, out);
    else       sk_final<false><<<gfin, 256, 0, stream>>>(Mat, rr, rc, out);
}

extern "C" void kernel_launch(void* const* d_in, const int* in_sizes, int n_in,
                              void* d_out, int out_size, void* d_ws, size_t ws_size,
                              hipStream_t stream) {
    const float* M   = (const float*)d_in[0];
    float*       out = (float*)d_out;
    char*        ws  = (char*)d_ws;

    // coop-path workspace:
    //   flags: flag_r[256] | flag_c[256]  (monotone generation counters)
    //   rpart[2][16*NN] f32 | cpart[2][16*NN] f32  (parity double-buffered)
    unsigned* flag_r = (unsigned*)ws;
    unsigned* flag_c = (unsigned*)(ws + 1024);
    float*    rpart  = (float*)(ws + 4096);
    float*    cpart  = (float*)(ws + 4096 + 2 * 16 * NN * sizeof(float));
    const size_t ws_need = 4096 + 4 * 16 * NN * sizeof(float);

    int dev = 0;
    (void)hipGetDevice(&dev);
    int coop = 0;
    (void)hipDeviceGetAttribute(&coop, hipDeviceAttributeCooperativeLaunch, dev);
    hipError_t eattr = hipFuncSetAttribute(
        (const void*)sk_coop, hipFuncAttributeMaxDynamicSharedMemorySize, SMEM_BYTES);

    bool done = false;
    if (coop && eattr == hipSuccess && ws_size >= ws_need) {
        sk_flag_init<<<1, 512, 0, stream>>>(flag_r);
        void* args[6] = {(void*)&M, (void*)&out, (void*)&rpart, (void*)&cpart,
                         (void*)&flag_r, (void*)&flag_c};
        hipError_t e = hipLaunchCooperativeKernel((void*)sk_coop, dim3(NBLK),
                                                  dim3(NTHR), args, SMEM_BYTES,
                                                  stream);
        done = (e == hipSuccess);
    }
    if (!done) launch_fallback(M, out, ws, ws_size, stream);
}

// Round 4
// 1018.892 us; speedup vs baseline: 2.1630x; 1.4096x over previous
//
#include <hip/hip_runtime.h>
#include <cstdint>
#include <cstddef>

#define NN 4096
#define ITERS 50
#define TB 256            // tile is TB x TB
#define TSTRIDE 264       // halves per LDS tile row (16B-aligned rows; uniform bank load)
#define NBLK 256          // 16 x 16 blocks
#define NTHR 1024

typedef _Float16 half4v __attribute__((ext_vector_type(4)));
typedef _Float16 half8v __attribute__((ext_vector_type(8)));

#define T_BYTES (TB * TSTRIDE * 2)                      // 135168
#define RED_FLOATS 4096                                 // red[16][256]
#define SMEM_BYTES (T_BYTES + RED_FLOATS * 4 + 1024 + 1024)   // 153600

#define SCOPE __HIP_MEMORY_SCOPE_AGENT

// ---------------------------------------------------------------------------
// Cooperative LDS-resident Sinkhorn, group-local sync.
//   E = exp(M) as fp16 tile in LDS. Per iteration:
//     rr[i] = 1/sum_j E[i,j]*rc[j]   (row step)
//     rc[j] = 1/sum_i E[i,j]*rr[i]   (col step, uses NEW rr)
// Cross-block protocol per sync:
//   writers: plain stores of partials -> __syncthreads (drains vmcnt to L2)
//            -> t==0 release-store of generation flag (wbl2 + sc1 store)
//   readers: 16 lanes spin on RELAXED agent loads (coherent, no inv per poll)
//            -> wave 0 executes ONE acquire fence (buffer_inv)
//            -> __syncthreads -> plain reads of partials (fresh lines)
// rpart/cpart double-buffered by iteration parity (lap hazard is >=2 syncs
// away by transitivity). Flags monotone generation counters, init'd once.
// Layouts: group partials contiguous 16 KB; group flags one 64 B line.
// ---------------------------------------------------------------------------

__global__ void sk_flag_init(unsigned* __restrict__ flags) {
    flags[threadIdx.x] = 0u;   // 512 words: flag_r[256] | flag_cT[256]
}

__global__ __launch_bounds__(NTHR) void sk_coop(const float* __restrict__ M,
                                                float* __restrict__ out,
                                                float* __restrict__ rpart,
                                                float* __restrict__ cpart,
                                                unsigned* __restrict__ flag_r,
                                                unsigned* __restrict__ flag_cT) {
    extern __shared__ char smem[];
    _Float16* T   = (_Float16*)smem;               // [TB][TSTRIDE]
    float*    red = (float*)(smem + T_BYTES);      // [16][256]
    float*    rcv = red + RED_FLOATS;              // [256]
    float*    rrv = rcv + 256;                     // [256]

    const int t  = threadIdx.x;
    const int bi = blockIdx.x >> 4;    // row group
    const int bj = blockIdx.x & 15;    // col group
    const float* Mt = M + ((size_t)bi * TB) * NN + (size_t)bj * TB;

    // ---- load tile: E = exp(M) -> fp16 LDS ----
    #pragma unroll
    for (int i = 0; i < 16; ++i) {
        int idx = t + i * NTHR;
        int r = idx >> 6, c4 = idx & 63;
        float4 m = *(const float4*)(Mt + (size_t)r * NN + c4 * 4);
        half4v h;
        h[0] = (_Float16)__expf(m.x);
        h[1] = (_Float16)__expf(m.y);
        h[2] = (_Float16)__expf(m.z);
        h[3] = (_Float16)__expf(m.w);
        *(half4v*)&T[r * TSTRIDE + c4 * 4] = h;
    }

    for (int it = 0; it < ITERS; ++it) {
        const int par = it & 1;
        float* rp = rpart + (size_t)par * (16 * NN);
        float* cp = cpart + (size_t)par * (16 * NN);

        // ---- rc prep: wait col-group phase-B(it-1), rcv = 1/colsum ----
        if (it == 0) {
            if (t < TB) rcv[t] = 1.0f;
            __syncthreads();
        } else {
            if (t < 16) {
                const unsigned want = (unsigned)it;
                while (__hip_atomic_load(&flag_cT[bj * 16 + t], __ATOMIC_RELAXED,
                                         SCOPE) < want) {
                    __builtin_amdgcn_s_sleep(1);
                }
            }
            if (t < 64) __builtin_amdgcn_fence(__ATOMIC_ACQUIRE, "agent");
            __syncthreads();
            if (t < TB) {
                const float* cprev = cpart + (size_t)((it - 1) & 1) * (16 * NN)
                                   + (size_t)bj * 16 * 256;
                float s = 0.0f;
                #pragma unroll
                for (int g = 0; g < 16; ++g) s += cprev[g * 256 + t];
                rcv[t] = 1.0f / s;
            }
            __syncthreads();
        }

        // ---- phase A: row sums. thread: row = t&255, q = t>>8 owns 64 cols ----
        {
            const int row = t & 255, q = t >> 8;
            const half8v* Trow = (const half8v*)&T[row * TSTRIDE + q * 64];
            const float4* rc4  = (const float4*)(rcv + q * 64);
            float s = 0.0f;
            #pragma unroll
            for (int k = 0; k < 8; ++k) {
                half8v hv = Trow[k];
                float4 c0 = rc4[2 * k];
                float4 c1 = rc4[2 * k + 1];
                s += (float)hv[0] * c0.x + (float)hv[1] * c0.y +
                     (float)hv[2] * c0.z + (float)hv[3] * c0.w +
                     (float)hv[4] * c1.x + (float)hv[5] * c1.y +
                     (float)hv[6] * c1.z + (float)hv[7] * c1.w;
            }
            red[q * 256 + row] = s;
        }
        __syncthreads();
        if (t < TB) {
            float s = red[t] + red[256 + t] + red[512 + t] + red[768 + t];
            rp[(bi * 16 + bj) * 256 + t] = s;
        }
        __syncthreads();
        if (t == 0)
            __hip_atomic_store(&flag_r[bi * 16 + bj], (unsigned)(it + 1),
                               __ATOMIC_RELEASE, SCOPE);

        // ---- wait row-group; rr prep ----
        if (t < 16) {
            const unsigned want = (unsigned)(it + 1);
            while (__hip_atomic_load(&flag_r[bi * 16 + t], __ATOMIC_RELAXED,
                                     SCOPE) < want) {
                __builtin_amdgcn_s_sleep(1);
            }
        }
        if (t < 64) __builtin_amdgcn_fence(__ATOMIC_ACQUIRE, "agent");
        __syncthreads();
        if (t < TB) {
            const float* rg = rp + (size_t)bi * 16 * 256;
            float s = 0.0f;
            #pragma unroll
            for (int g = 0; g < 16; ++g) s += rg[g * 256 + t];
            rrv[t] = 1.0f / s;
        }
        __syncthreads();

        // ---- phase B: col sums. ch = t&31 (8 cols), sub = t>>5 (8 rows) ----
        {
            const int ch = t & 31, sub = t >> 5;
            const int w = t >> 6, lane = t & 63;
            float acc[8] = {0, 0, 0, 0, 0, 0, 0, 0};
            #pragma unroll
            for (int r = 0; r < 8; ++r) {
                const int row = sub * 8 + r;
                half8v hv = *(const half8v*)&T[row * TSTRIDE + ch * 8];
                float rr = rrv[row];
                #pragma unroll
                for (int j = 0; j < 8; ++j) acc[j] += (float)hv[j] * rr;
            }
            #pragma unroll
            for (int j = 0; j < 8; ++j) acc[j] += __shfl_down(acc[j], 32);
            if (lane < 32) {
                const int rot = (lane >> 2) & 7;
                float* rd = red + w * 256 + ch * 8;
                #pragma unroll
                for (int jj = 0; jj < 8; ++jj) {
                    int j = (jj + rot) & 7;
                    rd[j] = acc[j];
                }
            }
        }
        __syncthreads();
        if (t < TB) {
            float s = 0.0f;
            #pragma unroll
            for (int w = 0; w < 16; ++w) s += red[w * 256 + t];
            cp[(bj * 16 + bi) * 256 + t] = s;
        }
        __syncthreads();
        if (t == 0)
            __hip_atomic_store(&flag_cT[bj * 16 + bi], (unsigned)(it + 1),
                               __ATOMIC_RELEASE, SCOPE);
    }

    // ---- epilogue: wait col-group final; rc; out = max(exp(M)*rr*rc, 1e-9) ----
    if (t < 16) {
        while (__hip_atomic_load(&flag_cT[bj * 16 + t], __ATOMIC_RELAXED,
                                 SCOPE) < (unsigned)ITERS) {
            __builtin_amdgcn_s_sleep(1);
        }
    }
    if (t < 64) __builtin_amdgcn_fence(__ATOMIC_ACQUIRE, "agent");
    __syncthreads();
    if (t < TB) {
        const float* cl = cpart + (size_t)((ITERS - 1) & 1) * (16 * NN)
                        + (size_t)bj * 16 * 256;
        float s = 0.0f;
        #pragma unroll
        for (int g = 0; g < 16; ++g) s += cl[g * 256 + t];
        rcv[t] = 1.0f / s;
    }
    __syncthreads();

    float* outt = out + ((size_t)bi * TB) * NN + (size_t)bj * TB;
    #pragma unroll
    for (int i = 0; i < 16; ++i) {
        int idx = t + i * NTHR;
        int r = idx >> 6, c4 = idx & 63;
        float4 m = *(const float4*)(Mt + (size_t)r * NN + c4 * 4);
        float rr = rrv[r];
        float4 c = ((const float4*)rcv)[c4];
        float4 o;
        o.x = fmaxf(__expf(m.x) * rr * c.x, 1e-9f);
        o.y = fmaxf(__expf(m.y) * rr * c.y, 1e-9f);
        o.z = fmaxf(__expf(m.z) * rr * c.z, 1e-9f);
        o.w = fmaxf(__expf(m.w) * rr * c.w, 1e-9f);
        *(float4*)(outt + (size_t)r * NN + c4 * 4) = o;
    }
}

// ===========================================================================
// Fallback multi-kernel path (round-1, known-good).
// ===========================================================================

__global__ __launch_bounds__(256) void sk_init(float* __restrict__ rc,
                                               float* __restrict__ c_sum) {
    int j = blockIdx.x * 256 + threadIdx.x;
    rc[j] = 1.0f;
    c_sum[j] = 0.0f;
}

__global__ __launch_bounds__(256) void sk_exp(const float* __restrict__ M,
                                              float* __restrict__ E) {
    size_t idx = ((size_t)blockIdx.x * 256 + threadIdx.x) * 4;
    float4 m = *(const float4*)(M + idx);
    float4 e;
    e.x = __expf(m.x); e.y = __expf(m.y); e.z = __expf(m.z); e.w = __expf(m.w);
    *(float4*)(E + idx) = e;
}

template<bool HAS_E>
__global__ __launch_bounds__(256) void sk_row(const float* __restrict__ Mat,
                                              const float* __restrict__ rc,
                                              float* __restrict__ rr) {
    const int wave = threadIdx.x >> 6;
    const int lane = threadIdx.x & 63;
    const int row  = blockIdx.x * 4 + wave;
    const float4* __restrict__ Mrow = (const float4*)(Mat + (size_t)row * NN);
    const float4* __restrict__ RC   = (const float4*)rc;
    float s = 0.0f;
    #pragma unroll 4
    for (int k = lane; k < NN / 4; k += 64) {
        float4 m = Mrow[k];
        float4 c = RC[k];
        if (!HAS_E) {
            m.x = __expf(m.x); m.y = __expf(m.y);
            m.z = __expf(m.z); m.w = __expf(m.w);
        }
        s += m.x * c.x + m.y * c.y + m.z * c.z + m.w * c.w;
    }
    #pragma unroll
    for (int off = 32; off > 0; off >>= 1) s += __shfl_down(s, off, 64);
    if (lane == 0) rr[row] = 1.0f / s;
}

template<bool HAS_E>
__global__ __launch_bounds__(256) void sk_col(const float* __restrict__ Mat,
                                              const float* __restrict__ rr,
                                              float* __restrict__ c_sum) {
    const int j  = blockIdx.x * 256 + threadIdx.x;
    const int r0 = blockIdx.y * 64;
    const float* __restrict__ rrp = rr + r0;
    const float* __restrict__ p   = Mat + (size_t)r0 * NN + j;
    float s = 0.0f;
    #pragma unroll 8
    for (int i = 0; i < 64; ++i) {
        float m = p[(size_t)i * NN];
        if (!HAS_E) m = __expf(m);
        s += m * rrp[i];
    }
    atomicAdd(&c_sum[j], s);
}

__global__ __launch_bounds__(256) void sk_recip(float* __restrict__ c_sum,
                                                float* __restrict__ rc) {
    int j = blockIdx.x * 256 + threadIdx.x;
    rc[j] = 1.0f / c_sum[j];
    c_sum[j] = 0.0f;
}

template<bool HAS_E>
__global__ __launch_bounds__(256) void sk_final(const float* __restrict__ Mat,
                                                const float* __restrict__ rr,
                                                const float* __restrict__ rc,
                                                float* __restrict__ out) {
    const int row = blockIdx.y;
    const int c4  = blockIdx.x * 256 + threadIdx.x;
    float4 m = ((const float4*)(Mat + (size_t)row * NN))[c4];
    if (!HAS_E) {
        m.x = __expf(m.x); m.y = __expf(m.y);
        m.z = __expf(m.z); m.w = __expf(m.w);
    }
    float4 c = ((const float4*)rc)[c4];
    float  r = rr[row];
    float4 o;
    o.x = fmaxf(m.x * r * c.x, 1e-9f);
    o.y = fmaxf(m.y * r * c.y, 1e-9f);
    o.z = fmaxf(m.z * r * c.z, 1e-9f);
    o.w = fmaxf(m.w * r * c.w, 1e-9f);
    ((float4*)out)[(size_t)row * (NN / 4) + c4] = o;
}

static void launch_fallback(const float* M, float* out, char* ws, size_t ws_size,
                            hipStream_t stream) {
    float* rc    = (float*)(ws);
    float* rr    = (float*)(ws + 16 * 1024);
    float* c_sum = (float*)(ws + 32 * 1024);
    float* E     = (float*)(ws + 64 * 1024);

    const size_t need_e = 64 * 1024 + (size_t)NN * NN * sizeof(float);
    const bool   has_e  = ws_size >= need_e;

    sk_init<<<NN / 256, 256, 0, stream>>>(rc, c_sum);

    const float* Mat = M;
    if (has_e) {
        sk_exp<<<(NN * (size_t)NN) / 1024, 256, 0, stream>>>(M, E);
        Mat = E;
    }

    dim3 gcol(16, 64);
    for (int it = 0; it < ITERS; ++it) {
        if (has_e) sk_row<true ><<<NN / 4, 256, 0, stream>>>(Mat, rc, rr);
        else       sk_row<false><<<NN / 4, 256, 0, stream>>>(Mat, rc, rr);
        if (has_e) sk_col<true ><<<gcol, 256, 0, stream>>>(Mat, rr, c_sum);
        else       sk_col<false><<<gcol, 256, 0, stream>>>(Mat, rr, c_sum);
        sk_recip<<<NN / 256, 256, 0, stream>>>(c_sum, rc);
    }

    dim3 gfin(4, NN);
    if (has_e) sk_final<true ><<<gfin, 256, 0, stream>>>(Mat, rr, rc, out);
    else       sk_final<false><<<gfin, 256, 0, stream>>>(Mat, rr, rc, out);
}

extern "C" void kernel_launch(void* const* d_in, const int* in_sizes, int n_in,
                              void* d_out, int out_size, void* d_ws, size_t ws_size,
                              hipStream_t stream) {
    const float* M   = (const float*)d_in[0];
    float*       out = (float*)d_out;
    char*        ws  = (char*)d_ws;

    // coop-path workspace:
    //   flag_r[256] | flag_cT[256]   (monotone generation counters, 2 KB)
    //   rpart[2][16*NN] f32 | cpart[2][16*NN] f32   (parity double-buffered)
    unsigned* flag_r  = (unsigned*)ws;
    unsigned* flag_cT = (unsigned*)(ws + 1024);
    float*    rpart   = (float*)(ws + 4096);
    float*    cpart   = (float*)(ws + 4096 + 2 * 16 * NN * sizeof(float));
    const size_t ws_need = 4096 + 4 * 16 * NN * sizeof(float);

    int dev = 0;
    (void)hipGetDevice(&dev);
    int coop = 0;
    (void)hipDeviceGetAttribute(&coop, hipDeviceAttributeCooperativeLaunch, dev);
    hipError_t eattr = hipFuncSetAttribute(
        (const void*)sk_coop, hipFuncAttributeMaxDynamicSharedMemorySize, SMEM_BYTES);

    bool done = false;
    if (coop && eattr == hipSuccess && ws_size >= ws_need) {
        sk_flag_init<<<1, 512, 0, stream>>>(flag_r);
        void* args[6] = {(void*)&M, (void*)&out, (void*)&rpart, (void*)&cpart,
                         (void*)&flag_r, (void*)&flag_cT};
        hipError_t e = hipLaunchCooperativeKernel((void*)sk_coop, dim3(NBLK),
                                                  dim3(NTHR), args, SMEM_BYTES,
                                                  stream);
        done = (e == hipSuccess);
    }
    if (!done) launch_fallback(M, out, ws, ws_size, stream);
}

// Round 5
// 523.964 us; speedup vs baseline: 4.2062x; 1.9446x over previous
//
#include <hip/hip_runtime.h>
#include <cstdint>
#include <cstddef>

#define NN 4096
#define ITERS 50
#define TB 256            // tile is TB x TB
#define TSTRIDE 264       // halves per LDS tile row (16B-aligned rows)
#define NBLK 256          // 16 x 16 blocks
#define NTHR 1024

typedef _Float16 half4v __attribute__((ext_vector_type(4)));
typedef _Float16 half8v __attribute__((ext_vector_type(8)));

#define T_BYTES (TB * TSTRIDE * 2)                      // 135168
#define RED_FLOATS 4096                                 // red[16][256]
#define SMEM_BYTES (T_BYTES + RED_FLOATS * 4 + 1024 + 1024)   // 153600

#define SCOPE __HIP_MEMORY_SCOPE_AGENT

// ---------------------------------------------------------------------------
// Cooperative LDS-resident Sinkhorn, group-local sync, zero cache-maintenance
// exchange protocol:
//   All cross-block partials are RELAXED agent-scope atomics (sc1: bypass
//   L1/L2, read/write LLC directly -> always coherent, no inv/wb needed).
//   writer: relaxed partial stores -> __syncthreads (HW drains vmcnt per wave
//           at barrier) -> s_waitcnt vmcnt(0) compiler-barrier -> relaxed
//           flag store (monotone generation counter).
//   reader: 16 lanes spin on relaxed flag loads -> __syncthreads -> relaxed
//           partial loads (LLC-fresh by construction).
// rpart/cpart double-buffered by iteration parity (lap hazard >= 2 syncs away
// by flag transitivity). Group partials contiguous 16 KB; group flags 64 B.
// ---------------------------------------------------------------------------

__global__ void sk_flag_init(unsigned* __restrict__ flags) {
    flags[threadIdx.x] = 0u;   // 512 words: flag_r[256] | flag_cT[256]
}

__device__ __forceinline__ float pload(const float* p) {
    return __hip_atomic_load(p, __ATOMIC_RELAXED, SCOPE);
}
__device__ __forceinline__ void pstore(float* p, float v) {
    __hip_atomic_store(p, v, __ATOMIC_RELAXED, SCOPE);
}

__global__ __launch_bounds__(NTHR) void sk_coop(const float* __restrict__ M,
                                                float* __restrict__ out,
                                                float* __restrict__ rpart,
                                                float* __restrict__ cpart,
                                                unsigned* __restrict__ flag_r,
                                                unsigned* __restrict__ flag_cT) {
    extern __shared__ char smem[];
    _Float16* T   = (_Float16*)smem;               // [TB][TSTRIDE]
    float*    red = (float*)(smem + T_BYTES);      // [16][256]
    float*    rcv = red + RED_FLOATS;              // [256]
    float*    rrv = rcv + 256;                     // [256]

    const int t  = threadIdx.x;
    const int bi = blockIdx.x >> 4;    // row group
    const int bj = blockIdx.x & 15;    // col group
    const float* Mt = M + ((size_t)bi * TB) * NN + (size_t)bj * TB;

    // ---- load tile: E = exp(M) -> fp16 LDS ----
    #pragma unroll
    for (int i = 0; i < 16; ++i) {
        int idx = t + i * NTHR;
        int r = idx >> 6, c4 = idx & 63;
        float4 m = *(const float4*)(Mt + (size_t)r * NN + c4 * 4);
        half4v h;
        h[0] = (_Float16)__expf(m.x);
        h[1] = (_Float16)__expf(m.y);
        h[2] = (_Float16)__expf(m.z);
        h[3] = (_Float16)__expf(m.w);
        *(half4v*)&T[r * TSTRIDE + c4 * 4] = h;
    }

    for (int it = 0; it < ITERS; ++it) {
        const int par = it & 1;
        float* rp = rpart + (size_t)par * (16 * NN);
        float* cp = cpart + (size_t)par * (16 * NN);

        // ---- rc prep: wait col-group phase-B(it-1), rcv = 1/colsum ----
        if (it == 0) {
            if (t < TB) rcv[t] = 1.0f;
            __syncthreads();
        } else {
            if (t < 16) {
                const unsigned want = (unsigned)it;
                while (__hip_atomic_load(&flag_cT[bj * 16 + t], __ATOMIC_RELAXED,
                                         SCOPE) < want) {
                    __builtin_amdgcn_s_sleep(1);
                }
            }
            __syncthreads();
            asm volatile("" ::: "memory");
            if (t < TB) {
                const float* cprev = cpart + (size_t)((it - 1) & 1) * (16 * NN)
                                   + (size_t)bj * 16 * 256;
                float s = 0.0f;
                #pragma unroll
                for (int g = 0; g < 16; ++g) s += pload(&cprev[g * 256 + t]);
                rcv[t] = 1.0f / s;
            }
            __syncthreads();
        }

        // ---- phase A: row sums. thread: row = t&255, q = t>>8 owns 64 cols ----
        {
            const int row = t & 255, q = t >> 8;
            const half8v* Trow = (const half8v*)&T[row * TSTRIDE + q * 64];
            const float4* rc4  = (const float4*)(rcv + q * 64);
            float s = 0.0f;
            #pragma unroll
            for (int k = 0; k < 8; ++k) {
                half8v hv = Trow[k];
                float4 c0 = rc4[2 * k];
                float4 c1 = rc4[2 * k + 1];
                s += (float)hv[0] * c0.x + (float)hv[1] * c0.y +
                     (float)hv[2] * c0.z + (float)hv[3] * c0.w +
                     (float)hv[4] * c1.x + (float)hv[5] * c1.y +
                     (float)hv[6] * c1.z + (float)hv[7] * c1.w;
            }
            red[q * 256 + row] = s;
        }
        __syncthreads();
        if (t < TB) {
            float s = red[t] + red[256 + t] + red[512 + t] + red[768 + t];
            pstore(&rp[(bi * 16 + bj) * 256 + t], s);
        }
        __syncthreads();
        if (t == 0) {
            asm volatile("s_waitcnt vmcnt(0)" ::: "memory");
            __hip_atomic_store(&flag_r[bi * 16 + bj], (unsigned)(it + 1),
                               __ATOMIC_RELAXED, SCOPE);
        }

        // ---- wait row-group; rr prep ----
        if (t < 16) {
            const unsigned want = (unsigned)(it + 1);
            while (__hip_atomic_load(&flag_r[bi * 16 + t], __ATOMIC_RELAXED,
                                     SCOPE) < want) {
                __builtin_amdgcn_s_sleep(1);
            }
        }
        __syncthreads();
        asm volatile("" ::: "memory");
        if (t < TB) {
            const float* rg = rp + (size_t)bi * 16 * 256;
            float s = 0.0f;
            #pragma unroll
            for (int g = 0; g < 16; ++g) s += pload(&rg[g * 256 + t]);
            rrv[t] = 1.0f / s;
        }
        __syncthreads();

        // ---- phase B: col sums. ch = t&31 (8 cols), sub = t>>5 (8 rows) ----
        {
            const int ch = t & 31, sub = t >> 5;
            const int w = t >> 6, lane = t & 63;
            float acc[8] = {0, 0, 0, 0, 0, 0, 0, 0};
            #pragma unroll
            for (int r = 0; r < 8; ++r) {
                const int row = sub * 8 + r;
                half8v hv = *(const half8v*)&T[row * TSTRIDE + ch * 8];
                float rr = rrv[row];
                #pragma unroll
                for (int j = 0; j < 8; ++j) acc[j] += (float)hv[j] * rr;
            }
            #pragma unroll
            for (int j = 0; j < 8; ++j) acc[j] += __shfl_down(acc[j], 32);
            if (lane < 32) {
                const int rot = (lane >> 2) & 7;
                float* rd = red + w * 256 + ch * 8;
                #pragma unroll
                for (int jj = 0; jj < 8; ++jj) {
                    int j = (jj + rot) & 7;
                    rd[j] = acc[j];
                }
            }
        }
        __syncthreads();
        if (t < TB) {
            float s = 0.0f;
            #pragma unroll
            for (int w = 0; w < 16; ++w) s += red[w * 256 + t];
            pstore(&cp[(bj * 16 + bi) * 256 + t], s);
        }
        __syncthreads();
        if (t == 0) {
            asm volatile("s_waitcnt vmcnt(0)" ::: "memory");
            __hip_atomic_store(&flag_cT[bj * 16 + bi], (unsigned)(it + 1),
                               __ATOMIC_RELAXED, SCOPE);
        }
    }

    // ---- epilogue: wait col-group final; rc; out = max(exp(M)*rr*rc, 1e-9) ----
    if (t < 16) {
        while (__hip_atomic_load(&flag_cT[bj * 16 + t], __ATOMIC_RELAXED,
                                 SCOPE) < (unsigned)ITERS) {
            __builtin_amdgcn_s_sleep(1);
        }
    }
    __syncthreads();
    asm volatile("" ::: "memory");
    if (t < TB) {
        const float* cl = cpart + (size_t)((ITERS - 1) & 1) * (16 * NN)
                        + (size_t)bj * 16 * 256;
        float s = 0.0f;
        #pragma unroll
        for (int g = 0; g < 16; ++g) s += pload(&cl[g * 256 + t]);
        rcv[t] = 1.0f / s;
    }
    __syncthreads();

    float* outt = out + ((size_t)bi * TB) * NN + (size_t)bj * TB;
    #pragma unroll
    for (int i = 0; i < 16; ++i) {
        int idx = t + i * NTHR;
        int r = idx >> 6, c4 = idx & 63;
        float4 m = *(const float4*)(Mt + (size_t)r * NN + c4 * 4);
        float rr = rrv[r];
        float4 c = ((const float4*)rcv)[c4];
        float4 o;
        o.x = fmaxf(__expf(m.x) * rr * c.x, 1e-9f);
        o.y = fmaxf(__expf(m.y) * rr * c.y, 1e-9f);
        o.z = fmaxf(__expf(m.z) * rr * c.z, 1e-9f);
        o.w = fmaxf(__expf(m.w) * rr * c.w, 1e-9f);
        *(float4*)(outt + (size_t)r * NN + c4 * 4) = o;
    }
}

// ===========================================================================
// Fallback multi-kernel path (round-1, known-good).
// ===========================================================================

__global__ __launch_bounds__(256) void sk_init(float* __restrict__ rc,
                                               float* __restrict__ c_sum) {
    int j = blockIdx.x * 256 + threadIdx.x;
    rc[j] = 1.0f;
    c_sum[j] = 0.0f;
}

__global__ __launch_bounds__(256) void sk_exp(const float* __restrict__ M,
                                              float* __restrict__ E) {
    size_t idx = ((size_t)blockIdx.x * 256 + threadIdx.x) * 4;
    float4 m = *(const float4*)(M + idx);
    float4 e;
    e.x = __expf(m.x); e.y = __expf(m.y); e.z = __expf(m.z); e.w = __expf(m.w);
    *(float4*)(E + idx) = e;
}

template<bool HAS_E>
__global__ __launch_bounds__(256) void sk_row(const float* __restrict__ Mat,
                                              const float* __restrict__ rc,
                                              float* __restrict__ rr) {
    const int wave = threadIdx.x >> 6;
    const int lane = threadIdx.x & 63;
    const int row  = blockIdx.x * 4 + wave;
    const float4* __restrict__ Mrow = (const float4*)(Mat + (size_t)row * NN);
    const float4* __restrict__ RC   = (const float4*)rc;
    float s = 0.0f;
    #pragma unroll 4
    for (int k = lane; k < NN / 4; k += 64) {
        float4 m = Mrow[k];
        float4 c = RC[k];
        if (!HAS_E) {
            m.x = __expf(m.x); m.y = __expf(m.y);
            m.z = __expf(m.z); m.w = __expf(m.w);
        }
        s += m.x * c.x + m.y * c.y + m.z * c.z + m.w * c.w;
    }
    #pragma unroll
    for (int off = 32; off > 0; off >>= 1) s += __shfl_down(s, off, 64);
    if (lane == 0) rr[row] = 1.0f / s;
}

template<bool HAS_E>
__global__ __launch_bounds__(256) void sk_col(const float* __restrict__ Mat,
                                              const float* __restrict__ rr,
                                              float* __restrict__ c_sum) {
    const int j  = blockIdx.x * 256 + threadIdx.x;
    const int r0 = blockIdx.y * 64;
    const float* __restrict__ rrp = rr + r0;
    const float* __restrict__ p   = Mat + (size_t)r0 * NN + j;
    float s = 0.0f;
    #pragma unroll 8
    for (int i = 0; i < 64; ++i) {
        float m = p[(size_t)i * NN];
        if (!HAS_E) m = __expf(m);
        s += m * rrp[i];
    }
    atomicAdd(&c_sum[j], s);
}

__global__ __launch_bounds__(256) void sk_recip(float* __restrict__ c_sum,
                                                float* __restrict__ rc) {
    int j = blockIdx.x * 256 + threadIdx.x;
    rc[j] = 1.0f / c_sum[j];
    c_sum[j] = 0.0f;
}

template<bool HAS_E>
__global__ __launch_bounds__(256) void sk_final(const float* __restrict__ Mat,
                                                const float* __restrict__ rr,
                                                const float* __restrict__ rc,
                                                float* __restrict__ out) {
    const int row = blockIdx.y;
    const int c4  = blockIdx.x * 256 + threadIdx.x;
    float4 m = ((const float4*)(Mat + (size_t)row * NN))[c4];
    if (!HAS_E) {
        m.x = __expf(m.x); m.y = __expf(m.y);
        m.z = __expf(m.z); m.w = __expf(m.w);
    }
    float4 c = ((const float4*)rc)[c4];
    float  r = rr[row];
    float4 o;
    o.x = fmaxf(m.x * r * c.x, 1e-9f);
    o.y = fmaxf(m.y * r * c.y, 1e-9f);
    o.z = fmaxf(m.z * r * c.z, 1e-9f);
    o.w = fmaxf(m.w * r * c.w, 1e-9f);
    ((float4*)out)[(size_t)row * (NN / 4) + c4] = o;
}

static void launch_fallback(const float* M, float* out, char* ws, size_t ws_size,
                            hipStream_t stream) {
    float* rc    = (float*)(ws);
    float* rr    = (float*)(ws + 16 * 1024);
    float* c_sum = (float*)(ws + 32 * 1024);
    float* E     = (float*)(ws + 64 * 1024);

    const size_t need_e = 64 * 1024 + (size_t)NN * NN * sizeof(float);
    const bool   has_e  = ws_size >= need_e;

    sk_init<<<NN / 256, 256, 0, stream>>>(rc, c_sum);

    const float* Mat = M;
    if (has_e) {
        sk_exp<<<(NN * (size_t)NN) / 1024, 256, 0, stream>>>(M, E);
        Mat = E;
    }

    dim3 gcol(16, 64);
    for (int it = 0; it < ITERS; ++it) {
        if (has_e) sk_row<true ><<<NN / 4, 256, 0, stream>>>(Mat, rc, rr);
        else       sk_row<false><<<NN / 4, 256, 0, stream>>>(Mat, rc, rr);
        if (has_e) sk_col<true ><<<gcol, 256, 0, stream>>>(Mat, rr, c_sum);
        else       sk_col<false><<<gcol, 256, 0, stream>>>(Mat, rr, c_sum);
        sk_recip<<<NN / 256, 256, 0, stream>>>(c_sum, rc);
    }

    dim3 gfin(4, NN);
    if (has_e) sk_final<true ><<<gfin, 256, 0, stream>>>(Mat, rr, rc, out);
    else       sk_final<false><<<gfin, 256, 0, stream>>>(Mat, rr, rc, out);
}

extern "C" void kernel_launch(void* const* d_in, const int* in_sizes, int n_in,
                              void* d_out, int out_size, void* d_ws, size_t ws_size,
                              hipStream_t stream) {
    const float* M   = (const float*)d_in[0];
    float*       out = (float*)d_out;
    char*        ws  = (char*)d_ws;

    // coop-path workspace:
    //   flag_r[256] | flag_cT[256]   (monotone generation counters, 2 KB)
    //   rpart[2][16*NN] f32 | cpart[2][16*NN] f32   (parity double-buffered)
    unsigned* flag_r  = (unsigned*)ws;
    unsigned* flag_cT = (unsigned*)(ws + 1024);
    float*    rpart   = (float*)(ws + 4096);
    float*    cpart   = (float*)(ws + 4096 + 2 * 16 * NN * sizeof(float));
    const size_t ws_need = 4096 + 4 * 16 * NN * sizeof(float);

    int dev = 0;
    (void)hipGetDevice(&dev);
    int coop = 0;
    (void)hipDeviceGetAttribute(&coop, hipDeviceAttributeCooperativeLaunch, dev);
    hipError_t eattr = hipFuncSetAttribute(
        (const void*)sk_coop, hipFuncAttributeMaxDynamicSharedMemorySize, SMEM_BYTES);

    bool done = false;
    if (coop && eattr == hipSuccess && ws_size >= ws_need) {
        sk_flag_init<<<1, 512, 0, stream>>>(flag_r);
        void* args[6] = {(void*)&M, (void*)&out, (void*)&rpart, (void*)&cpart,
                         (void*)&flag_r, (void*)&flag_cT};
        hipError_t e = hipLaunchCooperativeKernel((void*)sk_coop, dim3(NBLK),
                                                  dim3(NTHR), args, SMEM_BYTES,
                                                  stream);
        done = (e == hipSuccess);
    }
    if (!done) launch_fallback(M, out, ws, ws_size, stream);
}